// Round 5
// baseline (142.425 us; speedup 1.0000x reference)
//
#include <hip/hip_runtime.h>
#include <hip/hip_bf16.h>
#include <math.h>

// NT-Xent loss, fused flash-style. N=8192 rows, D=256.
//   k_norm: row L2-normalize fp32 -> bf16 (ws); zero sumexp + out
//   k_sim : bf16 MFMA, exp((sim-1)/T) in-register, row+col sums via symmetry
//   k_nll : exact fp32 pos dot + per-row nll + mean via atomicAdd
//
// History:
//   R1: 64x64 wave tile @ (256,2): ~280 demand -> spill, 77 us.
//   R2: 32x64 tile @ (256,3): budget 168 < demand -> spill, 82 us.
//   R3: 32x64 tile @ (256,2): no spill, k_sim 49.3 us.
//   R4: LDS double-buffer: REGRESSED (57). R5: halve LDS reads: -2 only.
//   R6: symmetry (row sums == col sums), 528 upper-tri tiles: k_sim 42.3.
//   R7: strip-balanced 512 persistent blocks: k_sim 41.5 (null). DIAGNOSIS
//       ACROSS R4-R7: per-strip period ~6-10K cycles vs <1.5K cycles of
//       actual pipe work. The barrier-synced global_load_lds drain
//       (__syncthreads -> s_waitcnt vmcnt(0), all waves in lockstep, only
//       2 blocks/CU of phase diversity) sets a latency floor per strip that
//       no block-to-work mapping can fix.
//   R8 (this): DELETE the LDS staging (guide common-mistake #7: fbf = 4 MB,
//       L2/L3-resident). bfrag loads go direct global — same 16-rows x 16B
//       pattern as afrag, 2 base pointers/strip + imm offsets. NO
//       __syncthreads in k_sim at all; waves independent; latency hidden by
//       8 waves/CU + vmcnt pipelining over the unrolled t-loop.
//       LDS=0, bank conflicts=0. Keep symmetry + strip-balanced persistence.
#define N_ROWS 8192
#define D_DIM  256
#define HALF_N 4096
#define INV_T      14.285714285714286f      // 1/0.07
#define SCALE_LOG2 20.609929155556620f      // log2(e)/0.07
#define NEG_SCALE  -20.609929155556620f
#define EPSV   1e-8f

typedef __attribute__((ext_vector_type(8))) short bf16x8;   // 8 bf16 = 4 VGPR
typedef __attribute__((ext_vector_type(4))) float f32x4;

__device__ inline unsigned short f2bf(float x) {
    unsigned int u = __float_as_uint(x);
    unsigned int r = (u + 0x7fffu + ((u >> 16) & 1u)) >> 16;   // RNE
    return (unsigned short)r;
}

// ---------------- kernel 1: normalize rows, emit bf16; zero accumulators ---
__global__ __launch_bounds__(256) void k_norm(const float* __restrict__ feat,
                                              unsigned short* __restrict__ fbf,
                                              float* __restrict__ sumexp,
                                              float* __restrict__ out) {
    const int tid = threadIdx.x;
    const int gid = blockIdx.x * 256 + tid;
    if (gid < N_ROWS) sumexp[gid] = 0.f;
    if (gid == 0) out[0] = 0.f;

    const int w = tid >> 6, lane = tid & 63;
    const int row = blockIdx.x * 4 + w;              // 2048 blocks * 4 rows
    const float4 v = ((const float4*)(feat + row * D_DIM))[lane];
    float ss = v.x*v.x + v.y*v.y + v.z*v.z + v.w*v.w;
    #pragma unroll
    for (int off = 32; off; off >>= 1) ss += __shfl_xor(ss, off);
    const float scale = 1.f / fmaxf(sqrtf(ss), EPSV);
    ushort4 o;
    o.x = f2bf(v.x * scale);
    o.y = f2bf(v.y * scale);
    o.z = f2bf(v.z * scale);
    o.w = f2bf(v.w * scale);
    ((ushort4*)(fbf + row * D_DIM))[lane] = o;
}

// ---------------- kernel 2: fused sim + exp + row/col-sum (symmetric) ------
// Work unit = strip (tile tt, jt): 256 rows x 32 cols, tt over the 528
// upper-triangle 256x256 tiles (rt >= cs), jt in [0,8). 4224 strips total,
// block b owns strips [(33b)>>2, (33(b+1))>>2)  (8 or 9; spans <= 2 tiles).
// 4 independent waves x 64 rows; A (64x256) in regs (128 VGPR). B fragments
// loaded DIRECT from global (L2/L3-resident, 2 base ptrs + imm offsets per
// strip) — no LDS, no barriers anywhere. 16 b128-equivalent global loads +
// 64 MFMA per wave per strip. Off-diag: rsum[r] in regs + csum[c] per strip
// (shfl over q + atomicAdd). Diag: full tile, diagonal masked, rsum only.
__global__ __launch_bounds__(256, 2) void k_sim(const unsigned short* __restrict__ fbf,
                                                float* __restrict__ sumexp) {
    const int tid  = threadIdx.x;
    const int lane = tid & 63;
    const int w    = tid >> 6;
    const int q    = lane >> 4, l15 = lane & 15;

    int g          = (33 * blockIdx.x) >> 2;          // first strip
    const int gEnd = (33 * (blockIdx.x + 1)) >> 2;    // one past last

    // decode tile of strip g: tt -> (rt, cs), rt >= cs
    const int tt0 = g >> 3;
    int rt = (int)((sqrtf(8.f * (float)tt0 + 1.f) - 1.f) * 0.5f);
    while ((rt + 1) * (rt + 2) / 2 <= tt0) ++rt;
    while (rt * (rt + 1) / 2 > tt0) --rt;
    int cs = tt0 - rt * (rt + 1) / 2;
    int jt = g & 7;

    bf16x8 afrag[8][4];
#define LOAD_A(rt_) do {                                                      \
        const int rowBase_ = (rt_) * 256 + w * 64;                            \
        _Pragma("unroll")                                                     \
        for (int t_ = 0; t_ < 8; ++t_)                                        \
            _Pragma("unroll")                                                 \
            for (int ri_ = 0; ri_ < 4; ++ri_)                                 \
                afrag[t_][ri_] = *(const bf16x8*)(fbf                         \
                    + (rowBase_ + ri_*16 + l15) * D_DIM + t_*32 + q*8);       \
    } while (0)

    float rsum[4][4];
#define ZERO_RSUM() do {                                                      \
        _Pragma("unroll")                                                     \
        for (int ri_ = 0; ri_ < 4; ++ri_)                                     \
            _Pragma("unroll")                                                 \
            for (int r_ = 0; r_ < 4; ++r_) rsum[ri_][r_] = 0.f;               \
    } while (0)

    // reduce each rsum over 16 cols (lanes of the quad) and atomically flush
#define FLUSH_RSUM(rt_) do {                                                  \
        const int rowBase_ = (rt_) * 256 + w * 64;                            \
        _Pragma("unroll")                                                     \
        for (int ri_ = 0; ri_ < 4; ++ri_)                                     \
            _Pragma("unroll")                                                 \
            for (int r_ = 0; r_ < 4; ++r_) {                                  \
                float s_ = rsum[ri_][r_];                                     \
                s_ += __shfl_xor(s_, 1);                                      \
                s_ += __shfl_xor(s_, 2);                                      \
                s_ += __shfl_xor(s_, 4);                                      \
                s_ += __shfl_xor(s_, 8);                                      \
                if (l15 == 0)                                                 \
                    atomicAdd(&sumexp[rowBase_ + ri_ * 16 + q * 4 + r_], s_); \
            }                                                                 \
    } while (0)

    LOAD_A(rt);
    ZERO_RSUM();

    while (true) {
        const int colBase = cs * 256 + jt * 32;
        const bool isDiag = (rt == cs);
        const int rowBase = rt * 256 + w * 64;

        // B-fragment base pointers for this strip: col c = colBase+ci*16+l15,
        // contiguous 8 bf16 at k = t*32 + q*8 -> 8 loads @ imm offset 64*t.
        const unsigned short* b0 = fbf + (size_t)(colBase      + l15) * D_DIM + q * 8;
        const unsigned short* b1 = fbf + (size_t)(colBase + 16 + l15) * D_DIM + q * 8;

        f32x4 acc[4][2];
        #pragma unroll
        for (int ri = 0; ri < 4; ++ri)
            #pragma unroll
            for (int ci = 0; ci < 2; ++ci) acc[ri][ci] = (f32x4){0.f, 0.f, 0.f, 0.f};

        #pragma unroll
        for (int t = 0; t < 8; ++t) {
            bf16x8 bfrag[2];
            bfrag[0] = *(const bf16x8*)(b0 + t * 32);
            bfrag[1] = *(const bf16x8*)(b1 + t * 32);
            #pragma unroll
            for (int ri = 0; ri < 4; ++ri)
                #pragma unroll
                for (int ci = 0; ci < 2; ++ci)
                    acc[ri][ci] = __builtin_amdgcn_mfma_f32_16x16x32_bf16(
                        afrag[t][ri], bfrag[ci], acc[ri][ci], 0, 0, 0);
        }

        // advance coordinates for strip g+1
        const bool more = (g + 1 < gEnd);
        int nrt = rt, ncs = cs, njt = jt + 1;
        if (njt == 8) {
            njt = 0; ncs = cs + 1;
            if (ncs > rt) { nrt = rt + 1; ncs = 0; }
        }
        // tile change: issue afrag reload now; latency hides under epilogue
        if (more && njt == 0) {
            FLUSH_RSUM(rt);        // uses old afrag-independent rsum state
            LOAD_A(nrt);
            ZERO_RSUM();
        }

        // epilogue: e = exp2(acc*S - S). C/D layout: col=l15, row=q*4+reg.
        if (isDiag) {
            #pragma unroll
            for (int ri = 0; ri < 4; ++ri) {
                const int trow = rowBase + ri * 16;
                #pragma unroll
                for (int ci = 0; ci < 2; ++ci) {
                    const int tcol = colBase + ci * 16;
                    if (trow == tcol) {            // diagonal 16x16 tile
                        #pragma unroll
                        for (int r = 0; r < 4; ++r) {
                            const float e = __builtin_amdgcn_exp2f(
                                __builtin_fmaf(acc[ri][ci][r], SCALE_LOG2, NEG_SCALE));
                            rsum[ri][r] += (q * 4 + r == l15) ? 0.f : e;
                        }
                    } else {
                        #pragma unroll
                        for (int r = 0; r < 4; ++r)
                            rsum[ri][r] += __builtin_amdgcn_exp2f(
                                __builtin_fmaf(acc[ri][ci][r], SCALE_LOG2, NEG_SCALE));
                    }
                }
            }
        } else {
            // off-diagonal (rt > cs): rsum for rows AND csum for cols
            float csum0 = 0.f, csum1 = 0.f;
            #pragma unroll
            for (int ri = 0; ri < 4; ++ri) {
                #pragma unroll
                for (int r = 0; r < 4; ++r) {
                    const float e0 = __builtin_amdgcn_exp2f(
                        __builtin_fmaf(acc[ri][0][r], SCALE_LOG2, NEG_SCALE));
                    const float e1 = __builtin_amdgcn_exp2f(
                        __builtin_fmaf(acc[ri][1][r], SCALE_LOG2, NEG_SCALE));
                    rsum[ri][r] += e0 + e1;
                    csum0 += e0;
                    csum1 += e1;
                }
            }
            // reduce csum over the 4 q-groups (block rows live across q)
            csum0 += __shfl_xor(csum0, 16); csum0 += __shfl_xor(csum0, 32);
            csum1 += __shfl_xor(csum1, 16); csum1 += __shfl_xor(csum1, 32);
            if (q == 0)      atomicAdd(&sumexp[colBase      + l15], csum0);
            else if (q == 1) atomicAdd(&sumexp[colBase + 16 + l15], csum1);
        }

        if (!more) break;
        rt = nrt; cs = ncs; jt = njt; ++g;
    }

    FLUSH_RSUM(rt);
#undef LOAD_A
#undef ZERO_RSUM
#undef FLUSH_RSUM
}

// ---------------- kernel 3: exact pos similarity + nll + mean --------------
__global__ __launch_bounds__(256) void k_nll(const float* __restrict__ feat,
                                             const float* __restrict__ sumexp,
                                             float* __restrict__ out) {
    __shared__ float red[4];
    const int tid = threadIdx.x, w = tid >> 6, lane = tid & 63;
    const int i  = blockIdx.x * 4 + w;
    const int pc = (i + HALF_N) & (N_ROWS - 1);
    const float4 a = ((const float4*)(feat + i  * D_DIM))[lane];
    const float4 b = ((const float4*)(feat + pc * D_DIM))[lane];
    float dab = a.x*b.x + a.y*b.y + a.z*b.z + a.w*b.w;
    float daa = a.x*a.x + a.y*a.y + a.z*a.z + a.w*a.w;
    float dbb = b.x*b.x + b.y*b.y + b.z*b.z + b.w*b.w;
    #pragma unroll
    for (int off = 32; off; off >>= 1) {
        dab += __shfl_xor(dab, off);
        daa += __shfl_xor(daa, off);
        dbb += __shfl_xor(dbb, off);
    }
    if (lane == 0) {
        const float pos = dab / (fmaxf(sqrtf(daa), EPSV) * fmaxf(sqrtf(dbb), EPSV));
        red[w] = INV_T + logf(sumexp[i]) - pos * INV_T;
    }
    __syncthreads();
    if (tid == 0)
        atomicAdd(out, (red[0] + red[1] + red[2] + red[3]) * (1.f / N_ROWS));
}

extern "C" void kernel_launch(void* const* d_in, const int* in_sizes, int n_in,
                              void* d_out, int out_size, void* d_ws, size_t ws_size,
                              hipStream_t stream) {
    const float* feat = (const float*)d_in[0];
    char* ws = (char*)d_ws;
    unsigned short* fbf = (unsigned short*)ws;                 // 4 MB bf16
    float* sumexp = (float*)(ws + 4u * 1024u * 1024u);         // 32 KB

    k_norm<<<N_ROWS / 4, 256, 0, stream>>>(feat, fbf, sumexp, (float*)d_out);
    k_sim <<<512,        256, 0, stream>>>(fbf, sumexp);
    k_nll <<<N_ROWS / 4, 256, 0, stream>>>(feat, sumexp, (float*)d_out);
}

// Round 6
// 123.770 us; speedup vs baseline: 1.1507x; 1.1507x over previous
//
#include <hip/hip_runtime.h>
#include <hip/hip_bf16.h>
#include <math.h>

// NT-Xent loss, fused flash-style. N=8192 rows, D=256.
//   k_norm: row L2-normalize fp32 -> bf16 (ws); zero sumexp + out
//   k_sim : bf16 MFMA, exp((sim-1)/T) in-register, row+col sums via symmetry
//   k_nll : exact fp32 pos dot + per-row nll + mean via atomicAdd
//
// History:
//   R1: 64x64 wave tile @ (256,2): ~280 demand -> spill, 77 us.
//   R2: 32x64 tile @ (256,3): budget 168 < demand -> spill, 82 us.
//   R3: 32x64 tile @ (256,2): no spill, k_sim 49.3 us.
//   R4: LDS double-buffer WITH vmcnt(0) drains: REGRESSED (57).
//   R5: 64 rows/wave (halved LDS reads): only -2 (47.2).
//   R6: symmetry (row sums == col sums), 528 upper-tri tiles: 42.3.
//   R7: strip-balanced 512 persistent blocks: 41.5 (null).
//   R8: B direct-from-global, no LDS: REGRESSED (59.3). MfmaUtil 11%:
//       per-wave B loads (4x traffic, no cross-wave amortization) serialize
//       on L2/HBM latency under register pressure. Also: the harness's
//       256 MiB workspace fill between iters THRASHES L3 -> B fetches pay
//       ~900-cyc HBM latency. Unifying diagnosis of R3-R8: every variant
//       exposes ~one HBM-class latency per strip because the staging wait
//       drains vmcnt(0) with only epilogue-length prefetch lead.
//   R9 (this): LDS staging back + T4 counted-vmcnt 2-deep pipeline.
//       Two 16 KB buffers; stage(g+2) issued right after the read-release
//       barrier; steady-state wait is s_waitcnt vmcnt(4) (strip g+1's DMA
//       stays in flight ACROSS the barrier) -- never vmcnt(0) in the loop.
//       Raw s_barrier + sched_barrier(0) pins (no __syncthreads drain).
//       DMA now has a full strip period (~1 us >> 900 cyc) to land.
#define N_ROWS 8192
#define D_DIM  256
#define HALF_N 4096
#define INV_T      14.285714285714286f      // 1/0.07
#define SCALE_LOG2 20.609929155556620f      // log2(e)/0.07
#define NEG_SCALE  -20.609929155556620f
#define EPSV   1e-8f

typedef __attribute__((ext_vector_type(8))) short bf16x8;   // 8 bf16 = 4 VGPR
typedef __attribute__((ext_vector_type(4))) float f32x4;

#define AS1 __attribute__((address_space(1)))
#define AS3 __attribute__((address_space(3)))

__device__ inline unsigned short f2bf(float x) {
    unsigned int u = __float_as_uint(x);
    unsigned int r = (u + 0x7fffu + ((u >> 16) & 1u)) >> 16;   // RNE
    return (unsigned short)r;
}

// ---------------- kernel 1: normalize rows, emit bf16; zero accumulators ---
__global__ __launch_bounds__(256) void k_norm(const float* __restrict__ feat,
                                              unsigned short* __restrict__ fbf,
                                              float* __restrict__ sumexp,
                                              float* __restrict__ out) {
    const int tid = threadIdx.x;
    const int gid = blockIdx.x * 256 + tid;
    if (gid < N_ROWS) sumexp[gid] = 0.f;
    if (gid == 0) out[0] = 0.f;

    const int w = tid >> 6, lane = tid & 63;
    const int row = blockIdx.x * 4 + w;              // 2048 blocks * 4 rows
    const float4 v = ((const float4*)(feat + row * D_DIM))[lane];
    float ss = v.x*v.x + v.y*v.y + v.z*v.z + v.w*v.w;
    #pragma unroll
    for (int off = 32; off; off >>= 1) ss += __shfl_xor(ss, off);
    const float scale = 1.f / fmaxf(sqrtf(ss), EPSV);
    ushort4 o;
    o.x = f2bf(v.x * scale);
    o.y = f2bf(v.y * scale);
    o.z = f2bf(v.z * scale);
    o.w = f2bf(v.w * scale);
    ((ushort4*)(fbf + row * D_DIM))[lane] = o;
}

// ---------------- kernel 2: fused sim + exp + row/col-sum (symmetric) ------
// Work unit = strip (tile tt, jt): 256 rows x 32 cols, tt over the 528
// upper-triangle 256x256 tiles (rt >= cs), jt in [0,8). 4224 strips total,
// block b owns strips [(33b)>>2, (33(b+1))>>2) (8 or 9; spans <= 2 tiles).
// 4 waves x 64 rows; A (64x256) in regs (128 VGPR). B strip = 16 KB LDS via
// global_load_lds w=16, XOR-16B-chunk swizzle (conflict-free ds_read_b128).
// 2-deep double buffer, counted vmcnt:
//   prologue: STAGE(g->buf0), STAGE(g+1->buf1)
//   iter g:   wait vmcnt(4)  [strip g landed; g+1 stays in flight]
//             s_barrier; compute from buf[p]; s_barrier
//             STAGE(g+2 -> buf[p]); exp epilogue; boundary flush/reload
__global__ __launch_bounds__(256, 2) void k_sim(const unsigned short* __restrict__ fbf,
                                                float* __restrict__ sumexp) {
    __shared__ __align__(16) char Bs[32768];       // 2 x 16 KB
    const int tid  = threadIdx.x;
    const int lane = tid & 63;
    const int w    = tid >> 6;
    const int q    = lane >> 4, l15 = lane & 15;

    int g          = (33 * blockIdx.x) >> 2;          // first strip
    const int gEnd = (33 * (blockIdx.x + 1)) >> 2;    // one past last

    // decode tile of strip g: tt -> (rt, cs), rt >= cs
    const int tt0 = g >> 3;
    int rt = (int)((sqrtf(8.f * (float)tt0 + 1.f) - 1.f) * 0.5f);
    while ((rt + 1) * (rt + 2) / 2 <= tt0) ++rt;
    while (rt * (rt + 1) / 2 > tt0) --rt;
    int cs = tt0 - rt * (rt + 1) / 2;
    int jt = g & 7;

#define ADV(rt_, cs_, jt_) do {                                               \
        if (++jt_ == 8) { jt_ = 0; if (++cs_ > rt_) { cs_ = 0; ++rt_; } }     \
    } while (0)

    int nrt = rt, ncs = cs, njt = jt;                 // coords of strip g+1
    ADV(nrt, ncs, njt);

#define STAGE(colRow0, par) do {                                              \
        const char* Bg_ = (const char*)fbf + (size_t)(colRow0) * 512;         \
        char* Bd_ = Bs + ((par) << 14);                                       \
        _Pragma("unroll")                                                     \
        for (int i_ = 0; i_ < 4; ++i_) {                                      \
            const int idx_ = i_ * 256 + tid;                                  \
            const int col_ = idx_ >> 5;                                       \
            const int cir_ = idx_ & 31;                                       \
            __builtin_amdgcn_global_load_lds(                                 \
                (const AS1 void*)(Bg_ + col_ * 512 + ((cir_ ^ (col_ & 7)) << 4)), \
                (AS3 void*)(Bd_ + idx_ * 16), 16, 0, 0);                      \
        }                                                                     \
    } while (0)

    bf16x8 afrag[8][4];
#define LOAD_A(rt_) do {                                                      \
        const int rowBase_ = (rt_) * 256 + w * 64;                            \
        _Pragma("unroll")                                                     \
        for (int t_ = 0; t_ < 8; ++t_)                                        \
            _Pragma("unroll")                                                 \
            for (int ri_ = 0; ri_ < 4; ++ri_)                                 \
                afrag[t_][ri_] = *(const bf16x8*)(fbf                         \
                    + (rowBase_ + ri_*16 + l15) * D_DIM + t_*32 + q*8);       \
    } while (0)

    float rsum[4][4];
#define ZERO_RSUM() do {                                                      \
        _Pragma("unroll")                                                     \
        for (int ri_ = 0; ri_ < 4; ++ri_)                                     \
            _Pragma("unroll")                                                 \
            for (int r_ = 0; r_ < 4; ++r_) rsum[ri_][r_] = 0.f;               \
    } while (0)

#define FLUSH_RSUM(rt_) do {                                                  \
        const int rowBase_ = (rt_) * 256 + w * 64;                            \
        _Pragma("unroll")                                                     \
        for (int ri_ = 0; ri_ < 4; ++ri_)                                     \
            _Pragma("unroll")                                                 \
            for (int r_ = 0; r_ < 4; ++r_) {                                  \
                float s_ = rsum[ri_][r_];                                     \
                s_ += __shfl_xor(s_, 1);                                      \
                s_ += __shfl_xor(s_, 2);                                      \
                s_ += __shfl_xor(s_, 4);                                      \
                s_ += __shfl_xor(s_, 8);                                      \
                if (l15 == 0)                                                 \
                    atomicAdd(&sumexp[rowBase_ + ri_ * 16 + q * 4 + r_], s_); \
            }                                                                 \
    } while (0)

    // prologue: stage strips g and g+1, load A for tile of g
    STAGE(cs * 256 + jt * 32, 0);
    STAGE(ncs * 256 + njt * 32, 1);
    LOAD_A(rt);
    ZERO_RSUM();

    int p = 0;
    while (true) {
        const int colBase = cs * 256 + jt * 32;
        const bool isDiag = (rt == cs);
        const int rowBase = rt * 256 + w * 64;

        // counted wait: strip g's 4 DMA chunks done; strip g+1's stay in
        // flight across the barrier. Last iteration has nothing in flight
        // behind it -> full drain.
        if (g + 1 < gEnd) asm volatile("s_waitcnt vmcnt(4)" ::: "memory");
        else              asm volatile("s_waitcnt vmcnt(0)" ::: "memory");
        __builtin_amdgcn_s_barrier();                 // buf[p] ready for all
        __builtin_amdgcn_sched_barrier(0);            // no ds_read hoist up

        const char* Bp = Bs + (p << 14);

        f32x4 acc[4][2];
        #pragma unroll
        for (int ri = 0; ri < 4; ++ri)
            #pragma unroll
            for (int ci = 0; ci < 2; ++ci) acc[ri][ci] = (f32x4){0.f, 0.f, 0.f, 0.f};

        #pragma unroll
        for (int t = 0; t < 8; ++t) {
            bf16x8 bfrag[2];
            #pragma unroll
            for (int ci = 0; ci < 2; ++ci) {
                const int c   = ci * 16 + l15;     // local col 0..31
                const int cir = t * 4 + q;         // k-chunk
                bfrag[ci] = *(const bf16x8*)(Bp + c * 512 + ((cir ^ (c & 7)) << 4));
            }
            #pragma unroll
            for (int ri = 0; ri < 4; ++ri)
                #pragma unroll
                for (int ci = 0; ci < 2; ++ci)
                    acc[ri][ci] = __builtin_amdgcn_mfma_f32_16x16x32_bf16(
                        afrag[t][ri], bfrag[ci], acc[ri][ci], 0, 0, 0);
        }

        __builtin_amdgcn_sched_barrier(0);            // pin reads above bar
        __builtin_amdgcn_s_barrier();                 // all done reading buf[p]

        // stage strip g+2 into buf[p]: a full strip period to land
        const bool more = (g + 1 < gEnd);
        int rt2 = nrt, cs2 = ncs, jt2 = njt;
        ADV(rt2, cs2, jt2);                           // coords of strip g+2
        if (g + 2 < gEnd) STAGE(cs2 * 256 + jt2 * 32, p);

        // epilogue: e = exp2(acc*S - S). C/D layout: col=l15, row=q*4+reg.
        if (isDiag) {
            #pragma unroll
            for (int ri = 0; ri < 4; ++ri) {
                const int trow = rowBase + ri * 16;
                #pragma unroll
                for (int ci = 0; ci < 2; ++ci) {
                    const int tcol = colBase + ci * 16;
                    if (trow == tcol) {            // diagonal 16x16 tile
                        #pragma unroll
                        for (int r = 0; r < 4; ++r) {
                            const float e = __builtin_amdgcn_exp2f(
                                __builtin_fmaf(acc[ri][ci][r], SCALE_LOG2, NEG_SCALE));
                            rsum[ri][r] += (q * 4 + r == l15) ? 0.f : e;
                        }
                    } else {
                        #pragma unroll
                        for (int r = 0; r < 4; ++r)
                            rsum[ri][r] += __builtin_amdgcn_exp2f(
                                __builtin_fmaf(acc[ri][ci][r], SCALE_LOG2, NEG_SCALE));
                    }
                }
            }
        } else {
            // off-diagonal (rt > cs): rsum for rows AND csum for cols
            float csum0 = 0.f, csum1 = 0.f;
            #pragma unroll
            for (int ri = 0; ri < 4; ++ri) {
                #pragma unroll
                for (int r = 0; r < 4; ++r) {
                    const float e0 = __builtin_amdgcn_exp2f(
                        __builtin_fmaf(acc[ri][0][r], SCALE_LOG2, NEG_SCALE));
                    const float e1 = __builtin_amdgcn_exp2f(
                        __builtin_fmaf(acc[ri][1][r], SCALE_LOG2, NEG_SCALE));
                    rsum[ri][r] += e0 + e1;
                    csum0 += e0;
                    csum1 += e1;
                }
            }
            // reduce csum over the 4 q-groups (block rows live across q)
            csum0 += __shfl_xor(csum0, 16); csum0 += __shfl_xor(csum0, 32);
            csum1 += __shfl_xor(csum1, 16); csum1 += __shfl_xor(csum1, 32);
            if (q == 0)      atomicAdd(&sumexp[colBase      + l15], csum0);
            else if (q == 1) atomicAdd(&sumexp[colBase + 16 + l15], csum1);
        }

        if (!more) break;
        // boundary: flush AFTER this strip's epilogue (R7 ordering), then
        // reload A for the next tile (latency overlaps next strip's wait).
        if (njt == 0) {
            FLUSH_RSUM(rt);
            LOAD_A(nrt);
            ZERO_RSUM();
        }
        rt = nrt; cs = ncs; jt = njt;
        nrt = rt2; ncs = cs2; njt = jt2;
        p ^= 1; ++g;
    }

    FLUSH_RSUM(rt);
#undef ADV
#undef STAGE
#undef LOAD_A
#undef ZERO_RSUM
#undef FLUSH_RSUM
}

// ---------------- kernel 3: exact pos similarity + nll + mean --------------
__global__ __launch_bounds__(256) void k_nll(const float* __restrict__ feat,
                                             const float* __restrict__ sumexp,
                                             float* __restrict__ out) {
    __shared__ float red[4];
    const int tid = threadIdx.x, w = tid >> 6, lane = tid & 63;
    const int i  = blockIdx.x * 4 + w;
    const int pc = (i + HALF_N) & (N_ROWS - 1);
    const float4 a = ((const float4*)(feat + i  * D_DIM))[lane];
    const float4 b = ((const float4*)(feat + pc * D_DIM))[lane];
    float dab = a.x*b.x + a.y*b.y + a.z*b.z + a.w*b.w;
    float daa = a.x*a.x + a.y*a.y + a.z*a.z + a.w*a.w;
    float dbb = b.x*b.x + b.y*b.y + b.z*b.z + b.w*b.w;
    #pragma unroll
    for (int off = 32; off; off >>= 1) {
        dab += __shfl_xor(dab, off);
        daa += __shfl_xor(daa, off);
        dbb += __shfl_xor(dbb, off);
    }
    if (lane == 0) {
        const float pos = dab / (fmaxf(sqrtf(daa), EPSV) * fmaxf(sqrtf(dbb), EPSV));
        red[w] = INV_T + logf(sumexp[i]) - pos * INV_T;
    }
    __syncthreads();
    if (tid == 0)
        atomicAdd(out, (red[0] + red[1] + red[2] + red[3]) * (1.f / N_ROWS));
}

extern "C" void kernel_launch(void* const* d_in, const int* in_sizes, int n_in,
                              void* d_out, int out_size, void* d_ws, size_t ws_size,
                              hipStream_t stream) {
    const float* feat = (const float*)d_in[0];
    char* ws = (char*)d_ws;
    unsigned short* fbf = (unsigned short*)ws;                 // 4 MB bf16
    float* sumexp = (float*)(ws + 4u * 1024u * 1024u);         // 32 KB

    k_norm<<<N_ROWS / 4, 256, 0, stream>>>(feat, fbf, sumexp, (float*)d_out);
    k_sim <<<512,        256, 0, stream>>>(fbf, sumexp);
    k_nll <<<N_ROWS / 4, 256, 0, stream>>>(feat, sumexp, (float*)d_out);
}